// Round 5
// baseline (363.104 us; speedup 1.0000x reference)
//
#include <hip/hip_runtime.h>
#include <stdint.h>

// Problem constants
#define S_LEN 2048
#define DIM   2048
#define NH    16
#define NKV   4
#define HD    128
#define QKV_E 3072   // (16 + 2*4) * 128

typedef unsigned short u16;
typedef __attribute__((ext_vector_type(8))) short short8;   // 8 x bf16 MFMA operand
typedef __attribute__((ext_vector_type(4))) float floatx4;  // MFMA accumulator

__device__ __forceinline__ u16 f2bf(float f) {
  unsigned u = __float_as_uint(f);
  u = u + 0x7fffu + ((u >> 16) & 1u);   // RNE
  return (u16)(u >> 16);
}
__device__ __forceinline__ float bf2f(u16 b) {
  return __uint_as_float(((unsigned)b) << 16);
}

__device__ __forceinline__ void gload16(const void* g, void* l) {
  __builtin_amdgcn_global_load_lds((const __attribute__((address_space(1))) void*)g,
                                   (__attribute__((address_space(3))) void*)l, 16, 0, 0);
}

// ---------------- fused f32 -> bf16 casts (x, wqkv, wo) ----------------
__global__ __launch_bounds__(256) void cast3(const float* __restrict__ x,
                                             const float* __restrict__ wq,
                                             const float* __restrict__ wo,
                                             u16* __restrict__ xb,
                                             u16* __restrict__ wqb,
                                             u16* __restrict__ wob) {
  const int n1 = 2097152;              // 4096*2048/4
  const int n2 = n1 + 1572864;         // + 3072*2048/4
  const int n3 = n2 + 1048576;         // + 2048*2048/4
  int i = blockIdx.x * 256 + threadIdx.x;
  for (; i < n3; i += gridDim.x * 256) {
    const float* s; u16* d; int j;
    if (i < n1)      { s = x;  d = xb;  j = i; }
    else if (i < n2) { s = wq; d = wqb; j = i - n1; }
    else             { s = wo; d = wob; j = i - n2; }
    float4 v = ((const float4*)s)[j];
    ushort4 o;
    o.x = f2bf(v.x); o.y = f2bf(v.y); o.z = f2bf(v.z); o.w = f2bf(v.w);
    ((ushort4*)d)[j] = o;
  }
}

// ---------------- 256x256 8-phase bf16 GEMM, C = A * B^T ----------------
// A [M][K], B [N][K] bf16; K multiple of 64. 512 threads, 8 waves (2M x 4N),
// wave tile 128x64. LDS 128KB: A/B double-buffered [2][256][64] bf16, each
// tile split in 2 halves of 128 LDS-rows (128B, row-XOR swizzled).
// Per tile: 4 phases {12 ds_read_b128 | stage 1 half | barrier | 16 MFMA |
// barrier}, counted vmcnt(4) once per tile.

#define FENCE() asm volatile("" ::: "memory")
#define BARF()  do { FENCE(); __builtin_amdgcn_s_barrier(); FENCE(); } while (0)

template <int OBF16>
__global__ __launch_bounds__(512, 2) void gemm256(const u16* __restrict__ A,
                                                  const u16* __restrict__ B,
                                                  float* __restrict__ C,
                                                  u16* __restrict__ Cb,
                                                  int M, int N, int K) {
  extern __shared__ char sm[];   // [A: 2*32KB][B: 2*32KB]
  const int tid  = threadIdx.x;
  const int wid  = tid >> 6;
  const int lane = tid & 63;
  const int gg   = lane >> 4;
  const int c16  = lane & 15;
  const int wm   = wid >> 2;       // 0..1
  const int wn   = wid & 3;        // 0..3
  const int m0 = blockIdx.y * 256;
  const int n0 = blockIdx.x * 256;
  const int NT = K >> 6;

  floatx4 acc[8][4] = {};

  // ---- staging helpers: one half (16KB = 128 LDS-rows of 128B), 2 issues/wave
  // A half h: LDS-row lr -> global tile row (lr>>6)*128 + h*64 + (lr&63)
  // B half g: LDS-row lr -> global tile row (lr>>5)*64  + g*32 + (lr&31)
  auto stageA = [&](int kt, int h) {
#pragma unroll
    for (int i = 0; i < 2; ++i) {
      int lr = wid * 16 + i * 8 + (lane >> 3);
      int sb = (lane & 7) * 16;
      int grow = (lr >> 6) * 128 + h * 64 + (lr & 63);
      const char* g = (const char*)(A + (size_t)(m0 + grow) * K + (size_t)kt * 64)
                      + (sb ^ ((lr & 7) << 4));
      gload16(g, sm + (kt & 1) * 32768 + h * 16384 + (wid * 16 + i * 8) * 128);
    }
  };
  auto stageB = [&](int kt, int g) {
#pragma unroll
    for (int i = 0; i < 2; ++i) {
      int lr = wid * 16 + i * 8 + (lane >> 3);
      int sb = (lane & 7) * 16;
      int grow = (lr >> 5) * 64 + g * 32 + (lr & 31);
      const char* gp = (const char*)(B + (size_t)(n0 + grow) * K + (size_t)kt * 64)
                       + (sb ^ ((lr & 7) << 4));
      gload16(gp, sm + 65536 + (kt & 1) * 32768 + g * 16384 + (wid * 16 + i * 8) * 128);
    }
  };

  // ---- prologue: tile0 (4 halves) + tile1 first halves
  stageA(0, 0); stageB(0, 0); stageA(0, 1); stageB(0, 1);
  stageA(1, 0); stageB(1, 0);
  asm volatile("s_waitcnt vmcnt(4)" ::: "memory");
  BARF();

#define GPHASE(MH, NG, STAGE_CODE)                                              \
  do {                                                                          \
    short8 af[4][2], bfv[2][2];                                                 \
    const char* Abase = sm + buf * 32768 + (MH) * 16384;                        \
    const char* Bbase = sm + 65536 + buf * 32768 + (NG) * 16384;                \
    _Pragma("unroll") for (int mm = 0; mm < 4; ++mm) {                          \
      int lr = wm * 64 + mm * 16 + c16;                                         \
      _Pragma("unroll") for (int ks = 0; ks < 2; ++ks)                          \
        af[mm][ks] = *(const short8*)(Abase + lr * 128 +                        \
                        ((ks * 64 + gg * 16) ^ ((lr & 7) << 4)));               \
    }                                                                           \
    _Pragma("unroll") for (int nn = 0; nn < 2; ++nn) {                          \
      int lr = wn * 32 + nn * 16 + c16;                                         \
      _Pragma("unroll") for (int ks = 0; ks < 2; ++ks)                          \
        bfv[nn][ks] = *(const short8*)(Bbase + lr * 128 +                       \
                        ((ks * 64 + gg * 16) ^ ((lr & 7) << 4)));               \
    }                                                                           \
    STAGE_CODE;                                                                 \
    BARF();                                                                     \
    __builtin_amdgcn_s_setprio(1);                                              \
    _Pragma("unroll") for (int mm = 0; mm < 4; ++mm)                            \
      _Pragma("unroll") for (int nn = 0; nn < 2; ++nn) {                        \
        acc[(MH)*4+mm][(NG)*2+nn] = __builtin_amdgcn_mfma_f32_16x16x32_bf16(    \
            af[mm][0], bfv[nn][0], acc[(MH)*4+mm][(NG)*2+nn], 0, 0, 0);         \
        acc[(MH)*4+mm][(NG)*2+nn] = __builtin_amdgcn_mfma_f32_16x16x32_bf16(    \
            af[mm][1], bfv[nn][1], acc[(MH)*4+mm][(NG)*2+nn], 0, 0, 0);         \
      }                                                                         \
    __builtin_amdgcn_s_setprio(0);                                              \
    FENCE();                                                                    \
  } while (0)

  for (int t = 0; t < NT; ++t) {
    const int buf = t & 1;
    GPHASE(0, 0, { if (t + 1 < NT) stageA(t + 1, 1); });
    BARF();
    GPHASE(0, 1, { if (t + 1 < NT) stageB(t + 1, 1); });
    BARF();
    GPHASE(1, 0, { if (t + 2 < NT) stageA(t + 2, 0); });
    BARF();
    GPHASE(1, 1, { if (t + 2 < NT) stageB(t + 2, 0); });
    if (t + 2 < NT) asm volatile("s_waitcnt vmcnt(4)" ::: "memory");
    else            asm volatile("s_waitcnt vmcnt(0)" ::: "memory");
    BARF();
  }
#undef GPHASE

  // ---- epilogue: D row = (lane>>4)*4 + r, col = lane&15 (verified layout)
#pragma unroll
  for (int mf = 0; mf < 8; ++mf)
#pragma unroll
    for (int nf = 0; nf < 4; ++nf) {
      int row = m0 + wm * 128 + mf * 16 + gg * 4;
      int col = n0 + wn * 64 + nf * 16 + c16;
      if (OBF16) {
        u16* cp = Cb + (size_t)row * N + col;
#pragma unroll
        for (int r = 0; r < 4; ++r) cp[(size_t)r * N] = f2bf(acc[mf][nf][r]);
      } else {
        float* cp = C + (size_t)row * N + col;
#pragma unroll
        for (int r = 0; r < 4; ++r) cp[(size_t)r * N] = acc[mf][nf][r];
      }
    }
}

// ---------------- RMSNorm + RoPE + split/cast ----------------
// qkv bf16 [B*S][3072] -> Qb [B][16][S][128] (pre-scaled by 1/sqrt(HD)),
//                         Kb [B][4][S][128], Vt [B][4][128][S] (transposed)
__global__ __launch_bounds__(256) void normrope(const u16* __restrict__ qkv,
                                                const float* __restrict__ freqs,
                                                const float* __restrict__ qw,
                                                const float* __restrict__ kw,
                                                u16* __restrict__ Qb,
                                                u16* __restrict__ Kb,
                                                u16* __restrict__ Vt) {
  int row  = blockIdx.x * 4 + (threadIdx.x >> 6);   // over B*S*24
  int lane = threadIdx.x & 63;
  int bs = row / 24, h = row % 24;
  int b = bs >> 11, s = bs & (S_LEN - 1);
  const u16* src = qkv + (size_t)bs * QKV_E + h * HD;
  ushort2 xr = *(const ushort2*)(src + 2 * lane);
  float x0 = bf2f(xr.x), x1 = bf2f(xr.y);

  float ss = x0 * x0 + x1 * x1;
#pragma unroll
  for (int off = 32; off; off >>= 1) ss += __shfl_xor(ss, off);
  float rn = rsqrtf(ss * (1.0f / 128.0f) + 1e-5f);

  const float scale = 0.08838834764831845f;  // 1/sqrt(128), folded into Q
  if (h < 20) {
    const float* w = (h < 16) ? qw : kw;
    float y0 = x0 * rn * w[2 * lane];
    float y1 = x1 * rn * w[2 * lane + 1];
    float2 f = *(const float2*)(freqs + (size_t)s * 128 + 2 * lane);  // cos, sin
    float r0 = y0 * f.x - y1 * f.y;
    float r1 = y1 * f.x + y0 * f.y;
    ushort2 o;
    if (h < 16) { o.x = f2bf(r0 * scale); o.y = f2bf(r1 * scale); }
    else        { o.x = f2bf(r0);         o.y = f2bf(r1); }
    u16* dst = (h < 16) ? (Qb + ((size_t)(b * NH  + h)      * S_LEN + s) * HD)
                        : (Kb + ((size_t)(b * NKV + h - 16) * S_LEN + s) * HD);
    *(ushort2*)(dst + 2 * lane) = o;
  } else {
    u16* dst = Vt + (size_t)(b * NKV + (h - 20)) * HD * S_LEN;
    dst[(size_t)(2 * lane)     * S_LEN + s] = f2bf(x0);
    dst[(size_t)(2 * lane + 1) * S_LEN + s] = f2bf(x1);
  }
}

// ---------------- MFMA flash attention (causal GQA, fixed-base softmax) ----
#define KT 64

__global__ __launch_bounds__(256) void attn_mfma(const u16* __restrict__ Qb,
                                                 const u16* __restrict__ Kb,
                                                 const u16* __restrict__ Vt,
                                                 u16* __restrict__ Yb) {
  __shared__ u16 Ks[KT * HD];          // 16 KB
  __shared__ u16 VtS[HD * KT];         // 16 KB
  __shared__ unsigned PsT[4][32 * 18]; // 9 KB

  const int wid  = threadIdx.x >> 6;
  const int lane = threadIdx.x & 63;
  const int gg   = lane >> 4;          // 16-lane group
  const int c16  = lane & 15;
  const int b = blockIdx.z, h = blockIdx.y, bx = blockIdx.x;
  const int hv = h >> 2;

  const u16* Qp = Qb + ((size_t)(b * NH  + h)  * S_LEN) * HD;
  const u16* Kp = Kb + ((size_t)(b * NKV + hv) * S_LEN) * HD;
  const u16* Vp = Vt + ((size_t)(b * NKV + hv) * HD) * S_LEN;

  short8 onesf;
#pragma unroll
  for (int i = 0; i < 8; ++i) onesf[i] = (short)0x3F80;  // bf16 1.0

  for (int pass = 0; pass < 2; ++pass) {
    const int qt  = pass ? (31 - bx) : bx;
    const int q0  = qt * 64;
    const int qw0 = q0 + wid * 16;     // this wave's first q row

    short8 qf[4];
    {
      const u16* qrow = Qp + (size_t)(qw0 + c16) * HD + gg * 8;
#pragma unroll
      for (int ds = 0; ds < 4; ++ds) qf[ds] = *(const short8*)(qrow + ds * 32);
    }

    floatx4 Oacc[8] = {};
    floatx4 Lacc = {};

    for (int k0 = 0; k0 < q0 + 64; k0 += KT) {
      // ---- stage K tile [64][128] (4 gload16/wave, 4 rows each)
#pragma unroll
      for (int i = 0; i < 4; ++i) {
        int rbase = wid * 16 + i * 4;
        int r = rbase + gg;
        int cb = c16 * 16;
        gload16((const char*)Kp + (size_t)(k0 + r) * 256 + (cb ^ ((r & 7) << 4)),
                (char*)Ks + rbase * 256);
      }
      // ---- stage Vt tile [128][64] (4 gload16/wave, 8 rows each)
#pragma unroll
      for (int i = 0; i < 4; ++i) {
        int rbase = wid * 32 + i * 8;
        int r = rbase + (lane >> 3);
        int cb = (lane & 7) * 16;
        gload16((const char*)Vp + (size_t)r * (S_LEN * 2) + (size_t)k0 * 2 + (cb ^ ((r & 7) << 4)),
                (char*)VtS + rbase * 128);
      }
      __syncthreads();

      if (k0 <= qw0 + 15) {   // wave has at least one unmasked (q,k)
        // ---- QK^T swapped: st[kt] = S^T tile, row=k_local, col=q
        floatx4 st[4] = {};
#pragma unroll
        for (int kt = 0; kt < 4; ++kt) {
          int krow = kt * 16 + c16;
          const char* kbase = (const char*)Ks + krow * 256;
          int swz = (krow & 7) << 4;
#pragma unroll
          for (int ds = 0; ds < 4; ++ds) {
            short8 kf = *(const short8*)(kbase + ((ds * 64 + gg * 16) ^ swz));
            st[kt] = __builtin_amdgcn_mfma_f32_16x16x32_bf16(kf, qf[ds], st[kt], 0, 0, 0);
          }
        }

        // ---- p = exp(s) (fixed-base softmax), mask, pack to P^T u32 pairs
        const int q = qw0 + c16;
        const bool full = (k0 + 63 <= qw0);
#pragma unroll
        for (int kt = 0; kt < 4; ++kt) {
          float p[4];
#pragma unroll
          for (int r = 0; r < 4; ++r) {
            int k = k0 + kt * 16 + gg * 4 + r;
            float e = __expf(st[kt][r]);
            p[r] = (full || k <= q) ? e : 0.f;
          }
          unsigned w0, w1;
          asm("v_cvt_pk_bf16_f32 %0, %1, %2" : "=v"(w0) : "v"(p[0]), "v"(p[1]));
          asm("v_cvt_pk_bf16_f32 %0, %1, %2" : "=v"(w1) : "v"(p[2]), "v"(p[3]));
          unsigned* pp = &PsT[wid][(kt * 8 + gg * 2) * 18 + c16];
          pp[0]  = w0;
          pp[18] = w1;
        }

        // ---- PV A-fragments from PsT (column read, pad-18 -> ~2-way)
        short8 pfr[2];
#pragma unroll
        for (int ktp = 0; ktp < 2; ++ktp) {
          const unsigned* pp = &PsT[wid][(ktp * 16 + gg * 4) * 18 + c16];
          unsigned u[4];
          u[0] = pp[0]; u[1] = pp[18]; u[2] = pp[36]; u[3] = pp[54];
          pfr[ktp] = *(const short8*)u;
        }

        // ---- row-sum l via ones-fragment MFMA
#pragma unroll
        for (int ktp = 0; ktp < 2; ++ktp)
          Lacc = __builtin_amdgcn_mfma_f32_16x16x32_bf16(pfr[ktp], onesf, Lacc, 0, 0, 0);

        // ---- PV
#pragma unroll
        for (int dt = 0; dt < 8; ++dt) {
          int vrow = dt * 16 + c16;
          int swzv = (vrow & 7) << 4;
#pragma unroll
          for (int ktp = 0; ktp < 2; ++ktp) {
            short8 vf = *(const short8*)((const char*)VtS + vrow * 128 + ((ktp * 64 + gg * 16) ^ swzv));
            Oacc[dt] = __builtin_amdgcn_mfma_f32_16x16x32_bf16(pfr[ktp], vf, Oacc[dt], 0, 0, 0);
          }
        }
      }
      __syncthreads();
    }

    // ---- epilogue: O / l -> Yb [b][s][h*128+d]
    float linv[4];
#pragma unroll
    for (int r = 0; r < 4; ++r) linv[r] = 1.0f / Lacc[r];
#pragma unroll
    for (int dt = 0; dt < 8; ++dt) {
      int d = dt * 16 + c16;
#pragma unroll
      for (int r = 0; r < 4; ++r) {
        int qg = qw0 + gg * 4 + r;
        Yb[((size_t)(b * S_LEN + qg)) * DIM + h * HD + d] = f2bf(Oacc[dt][r] * linv[r]);
      }
    }
  }
}

// ---------------- launch ----------------
extern "C" void kernel_launch(void* const* d_in, const int* in_sizes, int n_in,
                              void* d_out, int out_size, void* d_ws, size_t ws_size,
                              hipStream_t stream) {
  const float* x     = (const float*)d_in[0];
  const float* freqs = (const float*)d_in[1];
  const float* wqkv  = (const float*)d_in[3];
  const float* wo    = (const float*)d_in[4];
  const float* qw    = (const float*)d_in[5];
  const float* kw    = (const float*)d_in[6];
  float* out = (float*)d_out;
  char* ws = (char*)d_ws;

  const int M = 2 * S_LEN;  // 4096 rows (B*S)

  u16* xb    = (u16*)(ws);                 // 16 MB
  u16* wqkvb = (u16*)(ws + 16777216);      // 12 MB
  u16* wob   = (u16*)(ws + 29360128);      //  8 MB
  u16* qkvb  = (u16*)(ws + 37748736);      // 24 MB (bf16 GEMM output)
  u16* Qb    = (u16*)(ws + 62914560);      // 16 MB
  u16* Kb    = (u16*)(ws + 79691776);      //  4 MB
  u16* Vt    = (u16*)(ws + 83886080);      //  4 MB
  u16* Yb    = (u16*)(ws + 88080384);      // 16 MB  (end 100 MB)

  // allow 128KB dynamic LDS for the 8-phase GEMM (idempotent host-side calls)
  hipFuncSetAttribute((const void*)gemm256<1>,
                      hipFuncAttributeMaxDynamicSharedMemorySize, 131072);
  hipFuncSetAttribute((const void*)gemm256<0>,
                      hipFuncAttributeMaxDynamicSharedMemorySize, 131072);

  cast3<<<2048, 256, 0, stream>>>(x, wqkv, wo, xb, wqkvb, wob);

  gemm256<1><<<dim3(QKV_E / 256, M / 256), 512, 131072, stream>>>(
      xb, wqkvb, nullptr, qkvb, M, QKV_E, DIM);

  normrope<<<(M * 24) / 4, 256, 0, stream>>>(qkvb, freqs, qw, kw, Qb, Kb, Vt);

  attn_mfma<<<dim3(16, NH, 2), 256, 0, stream>>>(Qb, Kb, Vt, Yb);

  gemm256<0><<<dim3(DIM / 256, M / 256), 512, 131072, stream>>>(
      Yb, wob, out, nullptr, M, DIM, DIM);
}

// Round 6
// 325.328 us; speedup vs baseline: 1.1161x; 1.1161x over previous
//
#include <hip/hip_runtime.h>
#include <stdint.h>

// Problem constants
#define S_LEN 2048
#define DIM   2048
#define NH    16
#define NKV   4
#define HD    128
#define QKV_E 3072   // (16 + 2*4) * 128

typedef unsigned short u16;
typedef __attribute__((ext_vector_type(8))) short short8;   // 8 x bf16 MFMA operand
typedef __attribute__((ext_vector_type(4))) float floatx4;  // MFMA accumulator

__device__ __forceinline__ u16 f2bf(float f) {
  unsigned u = __float_as_uint(f);
  u = u + 0x7fffu + ((u >> 16) & 1u);   // RNE
  return (u16)(u >> 16);
}
__device__ __forceinline__ float bf2f(u16 b) {
  return __uint_as_float(((unsigned)b) << 16);
}

__device__ __forceinline__ void gload16(const void* g, void* l) {
  __builtin_amdgcn_global_load_lds((const __attribute__((address_space(1))) void*)g,
                                   (__attribute__((address_space(3))) void*)l, 16, 0, 0);
}

// ---------------- fused f32 -> bf16 casts (x, wqkv, wo) ----------------
__global__ __launch_bounds__(256) void cast3(const float* __restrict__ x,
                                             const float* __restrict__ wq,
                                             const float* __restrict__ wo,
                                             u16* __restrict__ xb,
                                             u16* __restrict__ wqb,
                                             u16* __restrict__ wob) {
  const int n1 = 2097152;              // 4096*2048/4
  const int n2 = n1 + 1572864;         // + 3072*2048/4
  const int n3 = n2 + 1048576;         // + 2048*2048/4
  int i = blockIdx.x * 256 + threadIdx.x;
  for (; i < n3; i += gridDim.x * 256) {
    const float* s; u16* d; int j;
    if (i < n1)      { s = x;  d = xb;  j = i; }
    else if (i < n2) { s = wq; d = wqb; j = i - n1; }
    else             { s = wo; d = wob; j = i - n2; }
    float4 v = ((const float4*)s)[j];
    ushort4 o;
    o.x = f2bf(v.x); o.y = f2bf(v.y); o.z = f2bf(v.z); o.w = f2bf(v.w);
    ((ushort4*)d)[j] = o;
  }
}

// ---------------- 8-phase bf16 GEMM, C = A * B^T, BMT x 256 tile ----------
// A [M][K], B [N][K] bf16; K mult of 64. 512 thr, 8 waves.
// BMT=256: wave 128x64, 4 phases/tile, 1.5-deep half-tile staging (verified
//          round-5 schedule), frags: af held per MH-half, bfv held per tile.
// BMT=128: wave 64x64, 2 phases/tile, 1-deep staging, counted vmcnt(4)/(2).
// LDS rows are 128B, row-XOR swizzle byte^=((row&7)<<4) on stage-src + reads.

#define FENCE() asm volatile("" ::: "memory")
#define BARF()  do { FENCE(); __builtin_amdgcn_s_barrier(); FENCE(); } while (0)

template <int OBF16, int BMT>
__global__ __launch_bounds__(512, 2) void gemm256(const u16* __restrict__ A,
                                                  const u16* __restrict__ B,
                                                  float* __restrict__ C,
                                                  u16* __restrict__ Cb,
                                                  int M, int N, int K) {
  extern __shared__ char sm[];   // [A: 2*ABUF][B: 2*32KB]
  constexpr int ABUF = BMT * 128;     // bytes per A k-tile buffer
  constexpr int BOFF = 2 * ABUF;
  const int tid  = threadIdx.x;
  const int wid  = tid >> 6;
  const int lane = tid & 63;
  const int gg   = lane >> 4;
  const int c16  = lane & 15;
  const int wm   = wid >> 2;       // 0..1
  const int wn   = wid & 3;        // 0..3
  const int m0 = blockIdx.y * BMT;
  const int n0 = blockIdx.x * 256;
  const int NT = K >> 6;

  floatx4 acc[(BMT == 256) ? 8 : 4][4] = {};
  short8 af[4][2], bfv0[2][2], bfv1[2][2];

  auto stageA = [&](int kt, int h) {
#pragma unroll
    for (int i = 0; i < 2; ++i) {
      int lr = wid * 16 + i * 8 + (lane >> 3);
      int sb = (lane & 7) * 16;
      int grow = (BMT == 256) ? ((lr >> 6) * 128 + h * 64 + (lr & 63)) : lr;
      const char* g = (const char*)(A + (size_t)(m0 + grow) * K + (size_t)kt * 64)
                      + (sb ^ ((lr & 7) << 4));
      gload16(g, sm + (kt & 1) * ABUF + h * 16384 + (wid * 16 + i * 8) * 128);
    }
  };
  auto stageB = [&](int kt, int g) {
#pragma unroll
    for (int i = 0; i < 2; ++i) {
      int lr = wid * 16 + i * 8 + (lane >> 3);
      int sb = (lane & 7) * 16;
      int grow = (lr >> 5) * 64 + g * 32 + (lr & 31);
      const char* gp = (const char*)(B + (size_t)(n0 + grow) * K + (size_t)kt * 64)
                       + (sb ^ ((lr & 7) << 4));
      gload16(gp, sm + BOFF + (kt & 1) * 32768 + g * 16384 + (wid * 16 + i * 8) * 128);
    }
  };
  auto loadA = [&](int buf, int mh) {
    const char* Ab = sm + buf * ABUF + mh * 16384;
#pragma unroll
    for (int mm = 0; mm < 4; ++mm) {
      int lr = wm * 64 + mm * 16 + c16;
#pragma unroll
      for (int ks = 0; ks < 2; ++ks)
        af[mm][ks] = *(const short8*)(Ab + lr * 128 +
                        ((ks * 64 + gg * 16) ^ ((lr & 7) << 4)));
    }
  };
  auto loadB = [&](int buf, int ng, short8 (&bfv)[2][2]) {
    const char* Bb = sm + BOFF + buf * 32768 + ng * 16384;
#pragma unroll
    for (int nn = 0; nn < 2; ++nn) {
      int lr = wn * 32 + nn * 16 + c16;
#pragma unroll
      for (int ks = 0; ks < 2; ++ks)
        bfv[nn][ks] = *(const short8*)(Bb + lr * 128 +
                        ((ks * 64 + gg * 16) ^ ((lr & 7) << 4)));
    }
  };
  auto mfma16 = [&](int mh, int ng, short8 (&bfv)[2][2]) {
    __builtin_amdgcn_s_setprio(1);
#pragma unroll
    for (int mm = 0; mm < 4; ++mm)
#pragma unroll
      for (int nn = 0; nn < 2; ++nn) {
        int mf = (BMT == 256) ? (mh * 4 + mm) : mm;
        acc[mf][ng * 2 + nn] = __builtin_amdgcn_mfma_f32_16x16x32_bf16(
            af[mm][0], bfv[nn][0], acc[mf][ng * 2 + nn], 0, 0, 0);
        acc[mf][ng * 2 + nn] = __builtin_amdgcn_mfma_f32_16x16x32_bf16(
            af[mm][1], bfv[nn][1], acc[mf][ng * 2 + nn], 0, 0, 0);
      }
    __builtin_amdgcn_s_setprio(0);
    FENCE();
  };

  if (BMT == 256) {
    // prologue: tile0 (4 halves) + tile1 halves-0
    stageA(0, 0); stageB(0, 0); stageA(0, 1); stageB(0, 1);
    stageA(1, 0); stageB(1, 0);
    asm volatile("s_waitcnt vmcnt(4)" ::: "memory");
    BARF();
    for (int t = 0; t < NT; ++t) {
      const int buf = t & 1;
      // ph0: (MH0,NG0)
      loadA(buf, 0); loadB(buf, 0, bfv0);
      if (t + 1 < NT) stageA(t + 1, 1);
      BARF(); mfma16(0, 0, bfv0); BARF();
      // ph1: (MH0,NG1)
      loadB(buf, 1, bfv1);
      if (t + 1 < NT) stageB(t + 1, 1);
      BARF(); mfma16(0, 1, bfv1); BARF();
      // ph2: (MH1,NG0)
      loadA(buf, 1);
      if (t + 2 < NT) stageA(t + 2, 0);
      BARF(); mfma16(1, 0, bfv0); BARF();
      // ph3: (MH1,NG1)
      if (t + 2 < NT) stageB(t + 2, 0);
      BARF(); mfma16(1, 1, bfv1);
      if (t + 2 < NT) asm volatile("s_waitcnt vmcnt(4)" ::: "memory");
      else            asm volatile("s_waitcnt vmcnt(0)" ::: "memory");
      BARF();
    }
  } else {
    // BMT=128: prologue tile0 (A, B0, B1)
    stageA(0, 0); stageB(0, 0); stageB(0, 1);
    asm volatile("s_waitcnt vmcnt(0)" ::: "memory");
    BARF();
    for (int t = 0; t < NT; ++t) {
      const int buf = t & 1;
      // ph0: NG0 (reads A + B0; stages A(t+1), B0(t+1))
      loadA(buf, 0); loadB(buf, 0, bfv0);
      if (t + 1 < NT) { stageA(t + 1, 0); stageB(t + 1, 0); }
      BARF(); mfma16(0, 0, bfv0);
      if (t + 1 < NT) asm volatile("s_waitcnt vmcnt(4)" ::: "memory");
      else            asm volatile("s_waitcnt vmcnt(0)" ::: "memory");
      BARF();
      // ph1: NG1 (reads B1; stages B1(t+1))
      loadB(buf, 1, bfv1);
      if (t + 1 < NT) stageB(t + 1, 1);
      BARF(); mfma16(0, 1, bfv1);
      if (t + 1 < NT) asm volatile("s_waitcnt vmcnt(2)" ::: "memory");
      BARF();
    }
  }

  // ---- epilogue: D row = (lane>>4)*4 + r, col = lane&15 (verified layout)
  constexpr int MFT = (BMT == 256) ? 8 : 4;
  constexpr int WROW = (BMT == 256) ? 128 : 64;
#pragma unroll
  for (int mf = 0; mf < MFT; ++mf)
#pragma unroll
    for (int nf = 0; nf < 4; ++nf) {
      int row = m0 + wm * WROW + mf * 16 + gg * 4;
      int col = n0 + wn * 64 + nf * 16 + c16;
      if (OBF16) {
        u16* cp = Cb + (size_t)row * N + col;
#pragma unroll
        for (int r = 0; r < 4; ++r) cp[(size_t)r * N] = f2bf(acc[mf][nf][r]);
      } else {
        float* cp = C + (size_t)row * N + col;
#pragma unroll
        for (int r = 0; r < 4; ++r) cp[(size_t)r * N] = acc[mf][nf][r];
      }
    }
}

// ---------------- RMSNorm + RoPE + split/cast ----------------
// qkv bf16 [B*S][3072] -> Qb [B][16][S][128] (pre-scaled by 1/sqrt(HD)),
//                         Kb [B][4][S][128], Vt [B][4][128][S] (transposed)
__global__ __launch_bounds__(256) void normrope(const u16* __restrict__ qkv,
                                                const float* __restrict__ freqs,
                                                const float* __restrict__ qw,
                                                const float* __restrict__ kw,
                                                u16* __restrict__ Qb,
                                                u16* __restrict__ Kb,
                                                u16* __restrict__ Vt) {
  int row  = blockIdx.x * 4 + (threadIdx.x >> 6);   // over B*S*24
  int lane = threadIdx.x & 63;
  int bs = row / 24, h = row % 24;
  int b = bs >> 11, s = bs & (S_LEN - 1);
  const u16* src = qkv + (size_t)bs * QKV_E + h * HD;
  ushort2 xr = *(const ushort2*)(src + 2 * lane);
  float x0 = bf2f(xr.x), x1 = bf2f(xr.y);

  float ss = x0 * x0 + x1 * x1;
#pragma unroll
  for (int off = 32; off; off >>= 1) ss += __shfl_xor(ss, off);
  float rn = rsqrtf(ss * (1.0f / 128.0f) + 1e-5f);

  const float scale = 0.08838834764831845f;  // 1/sqrt(128), folded into Q
  if (h < 20) {
    const float* w = (h < 16) ? qw : kw;
    float y0 = x0 * rn * w[2 * lane];
    float y1 = x1 * rn * w[2 * lane + 1];
    float2 f = *(const float2*)(freqs + (size_t)s * 128 + 2 * lane);  // cos, sin
    float r0 = y0 * f.x - y1 * f.y;
    float r1 = y1 * f.x + y0 * f.y;
    ushort2 o;
    if (h < 16) { o.x = f2bf(r0 * scale); o.y = f2bf(r1 * scale); }
    else        { o.x = f2bf(r0);         o.y = f2bf(r1); }
    u16* dst = (h < 16) ? (Qb + ((size_t)(b * NH  + h)      * S_LEN + s) * HD)
                        : (Kb + ((size_t)(b * NKV + h - 16) * S_LEN + s) * HD);
    *(ushort2*)(dst + 2 * lane) = o;
  } else {
    u16* dst = Vt + (size_t)(b * NKV + (h - 20)) * HD * S_LEN;
    dst[(size_t)(2 * lane)     * S_LEN + s] = f2bf(x0);
    dst[(size_t)(2 * lane + 1) * S_LEN + s] = f2bf(x1);
  }
}

// ---------------- MFMA flash attention (causal GQA, fixed-base softmax) ----
#define KT 64

__global__ __launch_bounds__(256) void attn_mfma(const u16* __restrict__ Qb,
                                                 const u16* __restrict__ Kb,
                                                 const u16* __restrict__ Vt,
                                                 u16* __restrict__ Yb) {
  __shared__ u16 Ks[KT * HD];          // 16 KB
  __shared__ u16 VtS[HD * KT];         // 16 KB
  __shared__ unsigned PsT[4][32 * 18]; // 9 KB

  const int wid  = threadIdx.x >> 6;
  const int lane = threadIdx.x & 63;
  const int gg   = lane >> 4;          // 16-lane group
  const int c16  = lane & 15;
  const int b = blockIdx.z, h = blockIdx.y, bx = blockIdx.x;
  const int hv = h >> 2;

  const u16* Qp = Qb + ((size_t)(b * NH  + h)  * S_LEN) * HD;
  const u16* Kp = Kb + ((size_t)(b * NKV + hv) * S_LEN) * HD;
  const u16* Vp = Vt + ((size_t)(b * NKV + hv) * HD) * S_LEN;

  short8 onesf;
#pragma unroll
  for (int i = 0; i < 8; ++i) onesf[i] = (short)0x3F80;  // bf16 1.0

  for (int pass = 0; pass < 2; ++pass) {
    const int qt  = pass ? (31 - bx) : bx;
    const int q0  = qt * 64;
    const int qw0 = q0 + wid * 16;     // this wave's first q row

    short8 qf[4];
    {
      const u16* qrow = Qp + (size_t)(qw0 + c16) * HD + gg * 8;
#pragma unroll
      for (int ds = 0; ds < 4; ++ds) qf[ds] = *(const short8*)(qrow + ds * 32);
    }

    floatx4 Oacc[8] = {};
    floatx4 Lacc = {};

    for (int k0 = 0; k0 < q0 + 64; k0 += KT) {
      // ---- stage K tile [64][128] (4 gload16/wave, 4 rows each)
#pragma unroll
      for (int i = 0; i < 4; ++i) {
        int rbase = wid * 16 + i * 4;
        int r = rbase + gg;
        int cb = c16 * 16;
        gload16((const char*)Kp + (size_t)(k0 + r) * 256 + (cb ^ ((r & 7) << 4)),
                (char*)Ks + rbase * 256);
      }
      // ---- stage Vt tile [128][64] (4 gload16/wave, 8 rows each)
#pragma unroll
      for (int i = 0; i < 4; ++i) {
        int rbase = wid * 32 + i * 8;
        int r = rbase + (lane >> 3);
        int cb = (lane & 7) * 16;
        gload16((const char*)Vp + (size_t)r * (S_LEN * 2) + (size_t)k0 * 2 + (cb ^ ((r & 7) << 4)),
                (char*)VtS + rbase * 128);
      }
      __syncthreads();

      if (k0 <= qw0 + 15) {   // wave has at least one unmasked (q,k)
        // ---- QK^T swapped: st[kt] = S^T tile, row=k_local, col=q
        floatx4 st[4] = {};
#pragma unroll
        for (int kt = 0; kt < 4; ++kt) {
          int krow = kt * 16 + c16;
          const char* kbase = (const char*)Ks + krow * 256;
          int swz = (krow & 7) << 4;
#pragma unroll
          for (int ds = 0; ds < 4; ++ds) {
            short8 kf = *(const short8*)(kbase + ((ds * 64 + gg * 16) ^ swz));
            st[kt] = __builtin_amdgcn_mfma_f32_16x16x32_bf16(kf, qf[ds], st[kt], 0, 0, 0);
          }
        }

        // ---- p = exp(s) (fixed-base softmax), mask, pack to P^T u32 pairs
        const int q = qw0 + c16;
        const bool full = (k0 + 63 <= qw0);
#pragma unroll
        for (int kt = 0; kt < 4; ++kt) {
          float p[4];
#pragma unroll
          for (int r = 0; r < 4; ++r) {
            int k = k0 + kt * 16 + gg * 4 + r;
            float e = __expf(st[kt][r]);
            p[r] = (full || k <= q) ? e : 0.f;
          }
          unsigned w0, w1;
          asm("v_cvt_pk_bf16_f32 %0, %1, %2" : "=v"(w0) : "v"(p[0]), "v"(p[1]));
          asm("v_cvt_pk_bf16_f32 %0, %1, %2" : "=v"(w1) : "v"(p[2]), "v"(p[3]));
          unsigned* pp = &PsT[wid][(kt * 8 + gg * 2) * 18 + c16];
          pp[0]  = w0;
          pp[18] = w1;
        }

        // ---- PV A-fragments from PsT (column read, pad-18 -> ~2-way)
        short8 pfr[2];
#pragma unroll
        for (int ktp = 0; ktp < 2; ++ktp) {
          const unsigned* pp = &PsT[wid][(ktp * 16 + gg * 4) * 18 + c16];
          unsigned u[4];
          u[0] = pp[0]; u[1] = pp[18]; u[2] = pp[36]; u[3] = pp[54];
          pfr[ktp] = *(const short8*)u;
        }

        // ---- row-sum l via ones-fragment MFMA
#pragma unroll
        for (int ktp = 0; ktp < 2; ++ktp)
          Lacc = __builtin_amdgcn_mfma_f32_16x16x32_bf16(pfr[ktp], onesf, Lacc, 0, 0, 0);

        // ---- PV
#pragma unroll
        for (int dt = 0; dt < 8; ++dt) {
          int vrow = dt * 16 + c16;
          int swzv = (vrow & 7) << 4;
#pragma unroll
          for (int ktp = 0; ktp < 2; ++ktp) {
            short8 vf = *(const short8*)((const char*)VtS + vrow * 128 + ((ktp * 64 + gg * 16) ^ swzv));
            Oacc[dt] = __builtin_amdgcn_mfma_f32_16x16x32_bf16(pfr[ktp], vf, Oacc[dt], 0, 0, 0);
          }
        }
      }
      __syncthreads();
    }

    // ---- epilogue: O / l -> Yb [b][s][h*128+d]
    float linv[4];
#pragma unroll
    for (int r = 0; r < 4; ++r) linv[r] = 1.0f / Lacc[r];
#pragma unroll
    for (int dt = 0; dt < 8; ++dt) {
      int d = dt * 16 + c16;
#pragma unroll
      for (int r = 0; r < 4; ++r) {
        int qg = qw0 + gg * 4 + r;
        Yb[((size_t)(b * S_LEN + qg)) * DIM + h * HD + d] = f2bf(Oacc[dt][r] * linv[r]);
      }
    }
  }
}

// ---------------- launch ----------------
extern "C" void kernel_launch(void* const* d_in, const int* in_sizes, int n_in,
                              void* d_out, int out_size, void* d_ws, size_t ws_size,
                              hipStream_t stream) {
  const float* x     = (const float*)d_in[0];
  const float* freqs = (const float*)d_in[1];
  const float* wqkv  = (const float*)d_in[3];
  const float* wo    = (const float*)d_in[4];
  const float* qw    = (const float*)d_in[5];
  const float* kw    = (const float*)d_in[6];
  float* out = (float*)d_out;
  char* ws = (char*)d_ws;

  const int M = 2 * S_LEN;  // 4096 rows (B*S)

  u16* xb    = (u16*)(ws);                 // 16 MB
  u16* wqkvb = (u16*)(ws + 16777216);      // 12 MB
  u16* wob   = (u16*)(ws + 29360128);      //  8 MB
  u16* qkvb  = (u16*)(ws + 37748736);      // 24 MB (bf16 GEMM output)
  u16* Qb    = (u16*)(ws + 62914560);      // 16 MB
  u16* Kb    = (u16*)(ws + 79691776);      //  4 MB
  u16* Vt    = (u16*)(ws + 83886080);      //  4 MB
  u16* Yb    = (u16*)(ws + 88080384);      // 16 MB  (end 100 MB)

  // dynamic LDS: 128KB (BMT=256), 96KB (BMT=128)
  hipFuncSetAttribute((const void*)gemm256<1, 256>,
                      hipFuncAttributeMaxDynamicSharedMemorySize, 131072);
  hipFuncSetAttribute((const void*)gemm256<0, 128>,
                      hipFuncAttributeMaxDynamicSharedMemorySize, 98304);

  cast3<<<2048, 256, 0, stream>>>(x, wqkv, wo, xb, wqkvb, wob);

  gemm256<1, 256><<<dim3(QKV_E / 256, M / 256), 512, 131072, stream>>>(
      xb, wqkvb, nullptr, qkvb, M, QKV_E, DIM);

  normrope<<<(M * 24) / 4, 256, 0, stream>>>(qkvb, freqs, qw, kw, Qb, Kb, Vt);

  attn_mfma<<<dim3(16, NH, 2), 256, 0, stream>>>(Qb, Kb, Vt, Yb);

  gemm256<0, 128><<<dim3(DIM / 256, M / 128), 512, 98304, stream>>>(
      Yb, wob, out, nullptr, M, DIM, DIM);
}